// Round 12
// baseline (440.801 us; speedup 1.0000x reference)
//
#include <hip/hip_runtime.h>
#include <hip/hip_bf16.h>
#include <cstdint>
#include <cstddef>

// GATv2: N=50000, E=400000, DIN=128, H=4, C=64, OUT=40
#define DIN 128
#define HC 256
#define OUTC 40
#define HOUT 160
#define NEG 0.2f
#define BNEPS 1e-5f

typedef float f32x4 __attribute__((ext_vector_type(4)));
typedef __bf16 bf16x8 __attribute__((ext_vector_type(8)));

struct __align__(8) bh4 { __hip_bfloat16 x, y, z, w; };
struct __align__(4) bh2 { __hip_bfloat16 x, y; };

__device__ __forceinline__ float4 ld4(const float* p) { return *(const float4*)p; }

__device__ __forceinline__ float4 ldb4(const __hip_bfloat16* p) {
    bh4 v = *(const bh4*)p;
    return make_float4(__bfloat162float(v.x), __bfloat162float(v.y),
                       __bfloat162float(v.z), __bfloat162float(v.w));
}

__device__ __forceinline__ float2 ldb2(const __hip_bfloat16* p) {
    bh2 v = *(const bh2*)p;
    return make_float2(__bfloat162float(v.x), __bfloat162float(v.y));
}

__device__ __forceinline__ void load_lds16(const void* g, void* l) {
    __builtin_amdgcn_global_load_lds((const __attribute__((address_space(1))) void*)g,
                                     (__attribute__((address_space(3))) void*)l, 16, 0, 0);
}

// ---------------------------------------------------------------------------
// bf16 MFMA GEMM (R5-verified): 128x128 tile, BK=32, 4 waves, XCD swizzle.
// LDS: As/Bs (16KB) UNION full-tile C staging (34.8KB), single barrier pair.
// ---------------------------------------------------------------------------
__global__ __launch_bounds__(256)
void gemm_mfma(const __hip_bfloat16* __restrict__ A, const __hip_bfloat16* __restrict__ Wt,
               const float* __restrict__ biasc, __hip_bfloat16* __restrict__ Y,
               int M, int K, int Npad, int gx, int q, int r) {
    __shared__ __hip_bfloat16 smem[128 * 136];     // 34816 B
    __hip_bfloat16* As = smem;
    __hip_bfloat16* Bs = smem + 128 * 32;
    const int tid = threadIdx.x;
    const int lane = tid & 63, wid = tid >> 6;
    const int wm = wid >> 1, wn = wid & 1;

    // bijective XCD-chunk swizzle (m204)
    const int orig = blockIdx.x;
    const int xcd = orig & 7, pos = orig >> 3;
    const int wgid = (xcd < r ? xcd * (q + 1) : r * (q + 1) + (xcd - r) * q) + pos;
    const int bn = (wgid % gx) * 128, bm = (wgid / gx) * 128;

    const int srow = lane >> 2;
    const int sseg = (lane & 3) * 8;
    f32x4 acc[4][4] = {};

    for (int k0 = 0; k0 < K; k0 += 32) {
#pragma unroll
        for (int i = 0; i < 2; ++i) {
            int c = 2 * wid + i;
            int ar = bm + 16 * c + srow; if (ar >= M) ar = M - 1;
            load_lds16(A + (size_t)ar * K + k0 + sseg, (char*)As + c * 1024);
            int br = bn + 16 * c + srow;
            load_lds16(Wt + (size_t)br * K + k0 + sseg, (char*)Bs + c * 1024);
        }
        __syncthreads();
        const int rkb = (lane >> 4) * 8;
        bf16x8 af[4], bfr[4];
#pragma unroll
        for (int i = 0; i < 4; ++i) {
            af[i]  = *(const bf16x8*)(As + (wm * 64 + i * 16 + (lane & 15)) * 32 + rkb);
            bfr[i] = *(const bf16x8*)(Bs + (wn * 64 + i * 16 + (lane & 15)) * 32 + rkb);
        }
#pragma unroll
        for (int mi = 0; mi < 4; ++mi)
#pragma unroll
            for (int ni = 0; ni < 4; ++ni)
                acc[mi][ni] = __builtin_amdgcn_mfma_f32_16x16x32_bf16(af[mi], bfr[ni], acc[mi][ni], 0, 0, 0);
        __syncthreads();
    }
    // stage C (+bias) into LDS (aliases As/Bs; safe after barrier)
    const int cl = lane & 15, rg4 = (lane >> 4) * 4;
#pragma unroll
    for (int ni = 0; ni < 4; ++ni) {
        float bv = biasc[bn + wn * 64 + ni * 16 + cl];
#pragma unroll
        for (int mi = 0; mi < 4; ++mi)
#pragma unroll
            for (int rr = 0; rr < 4; ++rr)
                smem[(wm * 64 + mi * 16 + rg4 + rr) * 136 + wn * 64 + ni * 16 + cl] =
                    __float2bfloat16(acc[mi][ni][rr] + bv);
    }
    __syncthreads();
#pragma unroll
    for (int it = 0; it < 8; ++it) {
        int row = it * 16 + (tid >> 4);
        int gm = bm + row;
        if (gm < M) {
            float4 v = *(const float4*)((const char*)(smem + row * 136) + (tid & 15) * 16);
            *(float4*)(Y + (size_t)gm * Npad + bn + (tid & 15) * 8) = v;
        }
    }
}

// ---------------------------------------------------------------------------
// Fused setup: f2b(x->xb) | weight prep (all 3 layers) | dst histogram.
// ---------------------------------------------------------------------------
#define T0 (768 * 128)
#define T1 (768 * 256)
#define T2 (384 * 256)
#define TT (T0 + T1 + T2)
__global__ __launch_bounds__(256)
void setup_kernel(
    const float* __restrict__ x, __hip_bfloat16* __restrict__ xb, int nf4,
    const int* __restrict__ dst, int* __restrict__ deg, int E,
    const float* __restrict__ Wl0, const float* __restrict__ bl0,
    const float* __restrict__ Wr0, const float* __restrict__ br0,
    const float* __restrict__ Ws0, const float* __restrict__ bs0,
    const float* __restrict__ Wl1, const float* __restrict__ bl1,
    const float* __restrict__ Wr1, const float* __restrict__ br1,
    const float* __restrict__ Ws1, const float* __restrict__ bs1,
    const float* __restrict__ Wl2, const float* __restrict__ bl2,
    const float* __restrict__ Wr2, const float* __restrict__ br2,
    const float* __restrict__ Ws2, const float* __restrict__ bs2,
    __hip_bfloat16* __restrict__ Wt0, float* __restrict__ bc0,
    __hip_bfloat16* __restrict__ Wt1, float* __restrict__ bc1,
    __hip_bfloat16* __restrict__ Wt2, float* __restrict__ bc2) {
    int idx = blockIdx.x * 256 + threadIdx.x;
    if (idx < nf4) {                                 // ---- f2b: x -> xb (4/thread)
        float4 v = ((const float4*)x)[idx];
        bh4 o;
        o.x = __float2bfloat16(v.x); o.y = __float2bfloat16(v.y);
        o.z = __float2bfloat16(v.z); o.w = __float2bfloat16(v.w);
        ((bh4*)xb)[idx] = o;
        return;
    }
    idx -= nf4;
    if (idx < TT) {                                  // ---- weight prep
        float v = 0.f, bb = 0.f;
        if (idx < T0) {                              // layer 0: K=128, Npad=768
            int n = idx / DIN, k = idx % DIN;
            if (n < 256)      { v = Wl0[(size_t)k * 256 + n];       bb = bl0[n]; }
            else if (n < 512) { v = Wr0[(size_t)k * 256 + n - 256]; bb = br0[n - 256]; }
            else              { v = Ws0[(size_t)k * 256 + n - 512]; bb = bs0[n - 512]; }
            Wt0[idx] = __float2bfloat16(v);
            if (k == 0) bc0[n] = bb;
        } else if (idx < T0 + T1) {                  // layer 1: K=256, Npad=768
            int i = idx - T0, n = i / HC, k = i % HC;
            if (n < 256)      { v = Wl1[(size_t)k * 256 + n];       bb = bl1[n]; }
            else if (n < 512) { v = Wr1[(size_t)k * 256 + n - 256]; bb = br1[n - 256]; }
            else              { v = Ws1[(size_t)k * 256 + n - 512]; bb = bs1[n - 512]; }
            Wt1[i] = __float2bfloat16(v);
            if (k == 0) bc1[n] = bb;
        } else {                                     // layer 2: K=256, Npad=384
            int i = idx - T0 - T1, n = i / HC, k = i % HC;
            if (n < 160)      { v = Wl2[(size_t)k * 160 + n];       bb = bl2[n]; }
            else if (n < 320) { v = Wr2[(size_t)k * 160 + n - 160]; bb = br2[n - 160]; }
            else if (n < 360) { v = Ws2[(size_t)k * 40 + n - 320];  bb = bs2[n - 320]; }
            Wt2[i] = __float2bfloat16(v);
            if (k == 0) bc2[n] = bb;
        }
        return;
    }
    idx -= TT;
    if (idx < E) atomicAdd(&deg[dst[idx]], 1);       // ---- dst histogram
}

// ---------------------------------------------------------------------------
// CSR scan: per-block exclusive scan (scan1), then merged offset+add (scan23).
// ---------------------------------------------------------------------------
__global__ __launch_bounds__(256)
void scan1_kernel(int* __restrict__ a, int* __restrict__ bsum, int n) {
    const int tid = threadIdx.x;
    const int i = blockIdx.x * 256 + tid;
    const int lane = tid & 63, w = tid >> 6;
    int v = (i < n) ? (a[i] + 1) : 0;
    int x = v;
#pragma unroll
    for (int s = 1; s < 64; s <<= 1) { int t = __shfl_up(x, s); if (lane >= s) x += t; }
    __shared__ int ws[4];
    if (lane == 63) ws[w] = x;
    __syncthreads();
    int bo = 0;
    if (w > 0) bo = ws[0];
    if (w > 1) bo += ws[1];
    if (w > 2) bo += ws[2];
    if (i <= n) a[i] = bo + x - v;
    if (tid == 255) bsum[blockIdx.x] = bo + x;
}

__global__ __launch_bounds__(256)
void scan23_kernel(int* __restrict__ a, const int* __restrict__ bsum, int n, int nb) {
    const int tid = threadIdx.x;
    const int lane = tid & 63, w = tid >> 6;
    int v = (tid < nb && tid < blockIdx.x) ? bsum[tid] : 0;
#pragma unroll
    for (int s = 1; s < 64; s <<= 1) v += __shfl_xor(v, s);
    __shared__ int ws[4];
    if (lane == 0) ws[w] = v;
    __syncthreads();
    int off = ws[0] + ws[1] + ws[2] + ws[3];
    int i = blockIdx.x * 256 + tid;
    if (i <= n) a[i] += off;
}

__global__ void scatter_kernel(const int* __restrict__ src, const int* __restrict__ dst,
                               const int* __restrict__ off, int* __restrict__ cursor,
                               int* __restrict__ srcs, int E, int N) {
    int e = blockIdx.x * 256 + threadIdx.x;
    if (e >= E + N) return;
    int s, d;
    if (e < E) { s = src[e]; d = dst[e]; }
    else       { s = e - E;  d = e - E; }
    int p = atomicAdd(&cursor[d], 1);
    srcs[off[d] + p] = s;
}

// ---------------------------------------------------------------------------
// GATv2 concat conv, HEAD-SPLIT: 2 waves per node (wave = node x head-pair).
// Lane owns 2 channels at cb = half*128 + 2*lane; head = 32-lane group;
// logit reduce = 5 shfl_xor (masks <32 stay in-group). No cross-wave comm.
// Doubles wave parallelism vs R10's 1-wave/node at LOWER VGPR.
// No-max softmax (logits O(1); clamp 50 = overflow insurance).
// ---------------------------------------------------------------------------
__device__ __forceinline__ float edge_logit2(const float2& xl, const float2& xr, const float2& av) {
    float e0 = xl.x + xr.x; e0 = e0 > 0.f ? e0 : NEG * e0;
    float e1 = xl.y + xr.y; e1 = e1 > 0.f ? e1 : NEG * e1;
    float p = e0 * av.x + e1 * av.y;
    p += __shfl_xor(p, 1);
    p += __shfl_xor(p, 2);
    p += __shfl_xor(p, 4);
    p += __shfl_xor(p, 8);
    p += __shfl_xor(p, 16);
    return fminf(p, 50.f);
}

template<bool BF16OUT>
__global__ __launch_bounds__(256)
void gat_conv_cat(const __hip_bfloat16* __restrict__ XL, const __hip_bfloat16* __restrict__ XR,
                  const __hip_bfloat16* __restrict__ SK, const float* __restrict__ att,
                  const float* __restrict__ bc,
                  const int* __restrict__ off, const int* __restrict__ srcs,
                  void* __restrict__ OUTv, int N, int RS) {
    const int wid = threadIdx.x >> 6;
    const int n = blockIdx.x * 2 + (wid >> 1);
    if (n >= N) return;
    const int half = wid & 1;
    const int lane = threadIdx.x & 63;
    const int cb = half * 128 + (lane << 1);       // 2 channels per lane
    const float2 xr = ldb2(XR + (size_t)n * RS + cb);
    const float2 av = *(const float2*)(att + cb);
    float z = 0.f, c0 = 0.f, c1 = 0.f;
    int j = off[n];
    const int e1 = off[n + 1];
    for (; j + 3 < e1; j += 4) {
        int s0 = srcs[j], s1 = srcs[j + 1], s2 = srcs[j + 2], s3 = srcs[j + 3];
        float2 x0 = ldb2(XL + (size_t)s0 * RS + cb);
        float2 x1 = ldb2(XL + (size_t)s1 * RS + cb);
        float2 x2 = ldb2(XL + (size_t)s2 * RS + cb);
        float2 x3 = ldb2(XL + (size_t)s3 * RS + cb);
        float a0 = __expf(edge_logit2(x0, xr, av));
        float a1 = __expf(edge_logit2(x1, xr, av));
        float a2 = __expf(edge_logit2(x2, xr, av));
        float a3 = __expf(edge_logit2(x3, xr, av));
        z += a0; c0 += a0 * x0.x; c1 += a0 * x0.y;
        z += a1; c0 += a1 * x1.x; c1 += a1 * x1.y;
        z += a2; c0 += a2 * x2.x; c1 += a2 * x2.y;
        z += a3; c0 += a3 * x3.x; c1 += a3 * x3.y;
    }
    for (; j < e1; ++j) {
        int s0 = srcs[j];
        float2 x0 = ldb2(XL + (size_t)s0 * RS + cb);
        float a0 = __expf(edge_logit2(x0, xr, av));
        z += a0; c0 += a0 * x0.x; c1 += a0 * x0.y;
    }
    float inv = 1.f / z;
    float2 sk = ldb2(SK + (size_t)n * RS + cb);
    float2 bb = *(const float2*)(bc + cb);
    float r0 = c0 * inv + bb.x + sk.x;
    float r1 = c1 * inv + bb.y + sk.y;
    if (BF16OUT) {
        bh2 o;
        o.x = __float2bfloat16(r0); o.y = __float2bfloat16(r1);
        *(bh2*)((__hip_bfloat16*)OUTv + (size_t)n * HC + cb) = o;
    } else {
        *(float2*)((float*)OUTv + (size_t)n * HC + cb) = make_float2(r0, r1);
    }
}

// ---------------------------------------------------------------------------
// GATv2 aggregation, mean layer (H=4, OUT=40). 2 nodes/wave, all 64 lanes.
// ---------------------------------------------------------------------------
__device__ __forceinline__ void mean_edge(const __hip_bfloat16* __restrict__ XL, size_t srow,
                                          int bm_ch, int bt_ch,
                                          const float4& xr4, float xrt,
                                          const float4& av4, float avt,
                                          float& z, float& c0, float& c1, float& c2,
                                          float& c3, float& c4) {
    float4 x4 = ldb4(XL + srow + bm_ch);
    float xt = __bfloat162float(XL[srow + bt_ch]);
    float e0 = x4.x + xr4.x; e0 = e0 > 0.f ? e0 : NEG * e0;
    float e1 = x4.y + xr4.y; e1 = e1 > 0.f ? e1 : NEG * e1;
    float e2 = x4.z + xr4.z; e2 = e2 > 0.f ? e2 : NEG * e2;
    float e3 = x4.w + xr4.w; e3 = e3 > 0.f ? e3 : NEG * e3;
    float et = xt + xrt;     et = et > 0.f ? et : NEG * et;
    float p = e0 * av4.x + e1 * av4.y + e2 * av4.z + e3 * av4.w + et * avt;
    p += __shfl_xor(p, 1);
    p += __shfl_xor(p, 2);
    p += __shfl_xor(p, 4);
    p = fminf(p, 50.f);
    float a = __expf(p);
    z += a;
    c0 += a * x4.x; c1 += a * x4.y; c2 += a * x4.z; c3 += a * x4.w; c4 += a * xt;
}

__global__ __launch_bounds__(256)
void gat_conv_mean(const __hip_bfloat16* __restrict__ XL, const __hip_bfloat16* __restrict__ XR,
                   const __hip_bfloat16* __restrict__ SK, const float* __restrict__ att,
                   const float* __restrict__ bc,
                   const int* __restrict__ off, const int* __restrict__ srcs,
                   float* __restrict__ OUT, int N, int RS) {
    const int lane = threadIdx.x & 63;
    const int half = lane >> 5, sub = lane & 31;
    const int n = blockIdx.x * 8 + (threadIdx.x >> 6) * 2 + half;
    if (n >= N) return;
    const int hd = sub >> 3, q = sub & 7;
    const int bm_ch = hd * OUTC + q * 4;
    const int bt_ch = hd * OUTC + 32 + q;
    const size_t nrow = (size_t)n * RS;
    const float4 xr4 = ldb4(XR + nrow + bm_ch);
    const float xrt = __bfloat162float(XR[nrow + bt_ch]);
    const float4 av4 = ld4(att + bm_ch);
    const float avt = att[bt_ch];
    float z = 0.f, c0 = 0.f, c1 = 0.f, c2 = 0.f, c3 = 0.f, c4 = 0.f;
    int j = off[n];
    const int e1 = off[n + 1];
    for (; j + 3 < e1; j += 4) {
        size_t r0 = (size_t)srcs[j] * RS,     r1 = (size_t)srcs[j + 1] * RS;
        size_t r2 = (size_t)srcs[j + 2] * RS, r3 = (size_t)srcs[j + 3] * RS;
        mean_edge(XL, r0, bm_ch, bt_ch, xr4, xrt, av4, avt, z, c0, c1, c2, c3, c4);
        mean_edge(XL, r1, bm_ch, bt_ch, xr4, xrt, av4, avt, z, c0, c1, c2, c3, c4);
        mean_edge(XL, r2, bm_ch, bt_ch, xr4, xrt, av4, avt, z, c0, c1, c2, c3, c4);
        mean_edge(XL, r3, bm_ch, bt_ch, xr4, xrt, av4, avt, z, c0, c1, c2, c3, c4);
    }
    for (; j < e1; ++j)
        mean_edge(XL, (size_t)srcs[j] * RS, bm_ch, bt_ch, xr4, xrt, av4, avt, z, c0, c1, c2, c3, c4);

    float inv = 1.f / z;
    float r0 = c0 * inv, r1 = c1 * inv, r2 = c2 * inv, r3 = c3 * inv, r4 = c4 * inv;
    r0 += __shfl_xor(r0, 8); r0 += __shfl_xor(r0, 16);
    r1 += __shfl_xor(r1, 8); r1 += __shfl_xor(r1, 16);
    r2 += __shfl_xor(r2, 8); r2 += __shfl_xor(r2, 16);
    r3 += __shfl_xor(r3, 8); r3 += __shfl_xor(r3, 16);
    r4 += __shfl_xor(r4, 8); r4 += __shfl_xor(r4, 16);
    if (hd == 0) {
        int o = q << 2;
        float4 sk4 = ldb4(SK + nrow + o);
        float skt = __bfloat162float(SK[nrow + 32 + q]);
        float4 rv;
        rv.x = r0 * 0.25f + bc[o + 0] + sk4.x;
        rv.y = r1 * 0.25f + bc[o + 1] + sk4.y;
        rv.z = r2 * 0.25f + bc[o + 2] + sk4.z;
        rv.w = r3 * 0.25f + bc[o + 3] + sk4.w;
        *(float4*)(OUT + (size_t)n * OUTC + o) = rv;
        OUT[(size_t)n * OUTC + 32 + q] = r4 * 0.25f + bc[32 + q] + skt;
    }
}

// ---------------------------------------------------------------------------
// BatchNorm stats (separate pass — fusing into conv regressed twice: R6, R8).
// ---------------------------------------------------------------------------
__global__ __launch_bounds__(256)
void bn_stats_f(const float* __restrict__ X, float* __restrict__ sums,
                float* __restrict__ sqs, int N) {
    int c = threadIdx.x;
    float s = 0.f, qq = 0.f;
    for (int n = blockIdx.x; n < N; n += gridDim.x) {
        float v = X[(size_t)n * HC + c];
        s += v; qq += v * v;
    }
    atomicAdd(&sums[c], s);
    atomicAdd(&sqs[c], qq);
}

__global__ __launch_bounds__(256)
void bn_stats_b(const __hip_bfloat16* __restrict__ X, float* __restrict__ sums,
                float* __restrict__ sqs, int N) {
    int c = threadIdx.x;
    float s = 0.f, qq = 0.f;
    for (int n = blockIdx.x; n < N; n += gridDim.x) {
        float v = __bfloat162float(X[(size_t)n * HC + c]);
        s += v; qq += v * v;
    }
    atomicAdd(&sums[c], s);
    atomicAdd(&sqs[c], qq);
}

// ---------------------------------------------------------------------------
// BN finalize (per-block, in LDS) + apply + ReLU -> bf16 (verified R8).
// ---------------------------------------------------------------------------
template<bool BF16IN>
__global__ __launch_bounds__(256)
void bn_apply_relu(const void* __restrict__ Xv, const float* __restrict__ sums,
                   const float* __restrict__ sqs, const float* __restrict__ g,
                   const float* __restrict__ be, __hip_bfloat16* __restrict__ Y,
                   int N, int n4) {
    __shared__ float scs[256], shs[256];
    {
        int c = threadIdx.x;
        float mean = sums[c] / (float)N;
        float var = sqs[c] / (float)N - mean * mean;
        float iv = rsqrtf(var + BNEPS);
        float sc = g[c] * iv;
        scs[c] = sc;
        shs[c] = be[c] - mean * sc;
    }
    __syncthreads();
    for (int i = blockIdx.x * blockDim.x + threadIdx.x; i < n4; i += gridDim.x * blockDim.x) {
        int c4 = (i & 63) << 2;
        float4 v;
        if (BF16IN) v = ldb4((const __hip_bfloat16*)Xv + (size_t)i * 4);
        else        v = ((const float4*)Xv)[i];
        float4 s = ld4(scs + c4);
        float4 h = ld4(shs + c4);
        bh4 r;
        r.x = __float2bfloat16(fmaxf(v.x * s.x + h.x, 0.f));
        r.y = __float2bfloat16(fmaxf(v.y * s.y + h.y, 0.f));
        r.z = __float2bfloat16(fmaxf(v.z * s.z + h.z, 0.f));
        r.w = __float2bfloat16(fmaxf(v.w * s.w + h.w, 0.f));
        ((bh4*)Y)[i] = r;
    }
}

// ---------------------------------------------------------------------------
extern "C" void kernel_launch(void* const* d_in, const int* in_sizes, int n_in,
                              void* d_out, int out_size, void* d_ws, size_t ws_size,
                              hipStream_t stream) {
    const int N = in_sizes[0] / DIN;    // 50000
    const int E = in_sizes[1];          // 400000
    const int Et = E + N;

    const float* x   = (const float*)d_in[0];
    const int* src   = (const int*)d_in[1];
    const int* dst   = (const int*)d_in[2];
    const float* Wl0 = (const float*)d_in[3];  const float* bl0 = (const float*)d_in[4];
    const float* Wr0 = (const float*)d_in[5];  const float* br0 = (const float*)d_in[6];
    const float* att0= (const float*)d_in[7];  const float* bc0 = (const float*)d_in[8];
    const float* Ws0 = (const float*)d_in[9];  const float* bs0 = (const float*)d_in[10];
    const float* g0  = (const float*)d_in[11]; const float* be0 = (const float*)d_in[12];
    const float* Wl1 = (const float*)d_in[13]; const float* bl1 = (const float*)d_in[14];
    const float* Wr1 = (const float*)d_in[15]; const float* br1 = (const float*)d_in[16];
    const float* att1= (const float*)d_in[17]; const float* bc1 = (const float*)d_in[18];
    const float* Ws1 = (const float*)d_in[19]; const float* bs1 = (const float*)d_in[20];
    const float* g1  = (const float*)d_in[21]; const float* be1 = (const float*)d_in[22];
    const float* Wl2 = (const float*)d_in[23]; const float* bl2 = (const float*)d_in[24];
    const float* Wr2 = (const float*)d_in[25]; const float* br2 = (const float*)d_in[26];
    const float* att2= (const float*)d_in[27]; const float* bc2 = (const float*)d_in[28];
    const float* Ws2 = (const float*)d_in[29]; const float* bs2 = (const float*)d_in[30];

    float* outh = (float*)d_out;                    // h [N,256] (layer-1 conv out, f32)
    float* outy = outh + (size_t)N * HC;            // out [N,40]

    // workspace carve (~132 MB)
    __hip_bfloat16* Y  = (__hip_bfloat16*)d_ws;     // [N][768] bf16 GEMM out
    __hip_bfloat16* xb = Y + (size_t)N * 768;       // [N][256] bf16 activations
    __hip_bfloat16* P  = xb + (size_t)N * HC;       // [N][256] bf16 x1pre staging
    __hip_bfloat16* Wt0 = P + (size_t)N * HC;       // [768*128]
    __hip_bfloat16* Wt1 = Wt0 + T0;                 // [768*256]
    __hip_bfloat16* Wt2 = Wt1 + T1;                 // [384*256]
    float* bcc0 = (float*)(Wt2 + T2);               // [768]
    float* bcc1 = bcc0 + 768;                       // [768]
    float* bcc2 = bcc1 + 768;                       // [384]
    int* off    = (int*)(bcc2 + 384);               // [N+1]
    int* cursor = off + (N + 1);                    // [N]
    float* bn   = (float*)(cursor + N);             // [1024]: s0,q0 | s1,q1
    int* srcs   = (int*)(bn + 1024);                // [Et]
    int* bsum   = srcs + Et;                        // [256]

    // ---- single memset: off + cursor + both BN accumulators ----
    hipMemsetAsync(off, 0, ((size_t)(2 * N + 1) + 1024) * sizeof(int), stream);

    // ---- fused setup (f2b | weight prep | histogram) ----
    const int nf4 = N * DIN / 4;
    const int setup_items = nf4 + TT + E;
    setup_kernel<<<(setup_items + 255) / 256, 256, 0, stream>>>(
        x, xb, nf4, dst, off, E,
        Wl0, bl0, Wr0, br0, Ws0, bs0, Wl1, bl1, Wr1, br1, Ws1, bs1,
        Wl2, bl2, Wr2, br2, Ws2, bs2, Wt0, bcc0, Wt1, bcc1, Wt2, bcc2);

    // ---- CSR scan + scatter ----
    const int nb_scan = (N + 1 + 255) / 256;        // 196
    scan1_kernel<<<nb_scan, 256, 0, stream>>>(off, bsum, N);
    scan23_kernel<<<nb_scan, 256, 0, stream>>>(off, bsum, N, nb_scan);
    scatter_kernel<<<(Et + 255) / 256, 256, 0, stream>>>(src, dst, off, cursor, srcs, E, N);

    const int gmy = (N + 127) / 128;                // 391 row tiles
    const int convGrid = (N + 1) / 2;               // head-split: 2 waves/node, 2 nodes/block
    const int meanGrid = (N + 7) / 8;
    const int nwgA = 6 * gmy, qA = nwgA / 8, rA = nwgA % 8;
    const int nwgC = 3 * gmy, qC = nwgC / 8, rC = nwgC % 8;

    // ---- layer 0 (K=128, Npad=768) ----
    gemm_mfma<<<nwgA, 256, 0, stream>>>(xb, Wt0, bcc0, Y, N, DIN, 768, 6, qA, rA);
    gat_conv_cat<true><<<convGrid, 256, 0, stream>>>(Y, Y + 256, Y + 512, att0, bc0,
                                                     off, srcs, P, N, 768);
    bn_stats_b<<<1024, 256, 0, stream>>>(P, bn, bn + 256, N);
    bn_apply_relu<true><<<2048, 256, 0, stream>>>(P, bn, bn + 256, g0, be0, xb, N, N * (HC / 4));

    // ---- layer 1 (K=256, Npad=768) ----
    gemm_mfma<<<nwgA, 256, 0, stream>>>(xb, Wt1, bcc1, Y, N, HC, 768, 6, qA, rA);
    gat_conv_cat<false><<<convGrid, 256, 0, stream>>>(Y, Y + 256, Y + 512, att1, bc1,
                                                      off, srcs, outh, N, 768);
    bn_stats_f<<<1024, 256, 0, stream>>>(outh, bn + 512, bn + 768, N);
    bn_apply_relu<false><<<2048, 256, 0, stream>>>(outh, bn + 512, bn + 768, g1, be1, xb, N, N * (HC / 4));

    // ---- layer 2 (K=256, Npad=384, cols: XL2[0:160) XR2[160:320) SK2[320:360)) ----
    gemm_mfma<<<nwgC, 256, 0, stream>>>(xb, Wt2, bcc2, Y, N, HC, 384, 3, qC, rC);
    gat_conv_mean<<<meanGrid, 256, 0, stream>>>(Y, Y + 160, Y + 320, att2, bc2, off, srcs,
                                                outy, N, 384);
}

// Round 13
// 396.801 us; speedup vs baseline: 1.1109x; 1.1109x over previous
//
#include <hip/hip_runtime.h>
#include <hip/hip_bf16.h>
#include <cstdint>
#include <cstddef>

// GATv2: N=50000, E=400000, DIN=128, H=4, C=64, OUT=40
#define DIN 128
#define HC 256
#define OUTC 40
#define HOUT 160
#define NEG 0.2f
#define BNEPS 1e-5f

typedef float f32x4 __attribute__((ext_vector_type(4)));
typedef __bf16 bf16x8 __attribute__((ext_vector_type(8)));

struct __align__(8) bh4 { __hip_bfloat16 x, y, z, w; };
struct __align__(16) bh8v { bh4 a, b; };

__device__ __forceinline__ float4 ld4(const float* p) { return *(const float4*)p; }

__device__ __forceinline__ float4 ldb4(const __hip_bfloat16* p) {
    bh4 v = *(const bh4*)p;
    return make_float4(__bfloat162float(v.x), __bfloat162float(v.y),
                       __bfloat162float(v.z), __bfloat162float(v.w));
}

__device__ __forceinline__ void ldb8(const __hip_bfloat16* p, float4& lo, float4& hi) {
    bh8v v = *(const bh8v*)p;
    lo = make_float4(__bfloat162float(v.a.x), __bfloat162float(v.a.y),
                     __bfloat162float(v.a.z), __bfloat162float(v.a.w));
    hi = make_float4(__bfloat162float(v.b.x), __bfloat162float(v.b.y),
                     __bfloat162float(v.b.z), __bfloat162float(v.b.w));
}

__device__ __forceinline__ void load_lds16(const void* g, void* l) {
    __builtin_amdgcn_global_load_lds((const __attribute__((address_space(1))) void*)g,
                                     (__attribute__((address_space(3))) void*)l, 16, 0, 0);
}

// ---------------------------------------------------------------------------
// bf16 MFMA GEMM (R5-verified): 128x128 tile, BK=32, 4 waves, XCD swizzle.
// LDS: As/Bs (16KB) UNION full-tile C staging (34.8KB), single barrier pair.
// ---------------------------------------------------------------------------
__global__ __launch_bounds__(256)
void gemm_mfma(const __hip_bfloat16* __restrict__ A, const __hip_bfloat16* __restrict__ Wt,
               const float* __restrict__ biasc, __hip_bfloat16* __restrict__ Y,
               int M, int K, int Npad, int gx, int q, int r) {
    __shared__ __hip_bfloat16 smem[128 * 136];     // 34816 B
    __hip_bfloat16* As = smem;
    __hip_bfloat16* Bs = smem + 128 * 32;
    const int tid = threadIdx.x;
    const int lane = tid & 63, wid = tid >> 6;
    const int wm = wid >> 1, wn = wid & 1;

    // bijective XCD-chunk swizzle (m204)
    const int orig = blockIdx.x;
    const int xcd = orig & 7, pos = orig >> 3;
    const int wgid = (xcd < r ? xcd * (q + 1) : r * (q + 1) + (xcd - r) * q) + pos;
    const int bn = (wgid % gx) * 128, bm = (wgid / gx) * 128;

    const int srow = lane >> 2;
    const int sseg = (lane & 3) * 8;
    f32x4 acc[4][4] = {};

    for (int k0 = 0; k0 < K; k0 += 32) {
#pragma unroll
        for (int i = 0; i < 2; ++i) {
            int c = 2 * wid + i;
            int ar = bm + 16 * c + srow; if (ar >= M) ar = M - 1;
            load_lds16(A + (size_t)ar * K + k0 + sseg, (char*)As + c * 1024);
            int br = bn + 16 * c + srow;
            load_lds16(Wt + (size_t)br * K + k0 + sseg, (char*)Bs + c * 1024);
        }
        __syncthreads();
        const int rkb = (lane >> 4) * 8;
        bf16x8 af[4], bfr[4];
#pragma unroll
        for (int i = 0; i < 4; ++i) {
            af[i]  = *(const bf16x8*)(As + (wm * 64 + i * 16 + (lane & 15)) * 32 + rkb);
            bfr[i] = *(const bf16x8*)(Bs + (wn * 64 + i * 16 + (lane & 15)) * 32 + rkb);
        }
#pragma unroll
        for (int mi = 0; mi < 4; ++mi)
#pragma unroll
            for (int ni = 0; ni < 4; ++ni)
                acc[mi][ni] = __builtin_amdgcn_mfma_f32_16x16x32_bf16(af[mi], bfr[ni], acc[mi][ni], 0, 0, 0);
        __syncthreads();
    }
    // stage C (+bias) into LDS (aliases As/Bs; safe after barrier)
    const int cl = lane & 15, rg4 = (lane >> 4) * 4;
#pragma unroll
    for (int ni = 0; ni < 4; ++ni) {
        float bv = biasc[bn + wn * 64 + ni * 16 + cl];
#pragma unroll
        for (int mi = 0; mi < 4; ++mi)
#pragma unroll
            for (int rr = 0; rr < 4; ++rr)
                smem[(wm * 64 + mi * 16 + rg4 + rr) * 136 + wn * 64 + ni * 16 + cl] =
                    __float2bfloat16(acc[mi][ni][rr] + bv);
    }
    __syncthreads();
#pragma unroll
    for (int it = 0; it < 8; ++it) {
        int row = it * 16 + (tid >> 4);
        int gm = bm + row;
        if (gm < M) {
            float4 v = *(const float4*)((const char*)(smem + row * 136) + (tid & 15) * 16);
            *(float4*)(Y + (size_t)gm * Npad + bn + (tid & 15) * 8) = v;
        }
    }
}

// ---------------------------------------------------------------------------
// Fused setup: f2b(x->xb) | weight prep (all 3 layers) | dst histogram.
// ---------------------------------------------------------------------------
#define T0 (768 * 128)
#define T1 (768 * 256)
#define T2 (384 * 256)
#define TT (T0 + T1 + T2)
__global__ __launch_bounds__(256)
void setup_kernel(
    const float* __restrict__ x, __hip_bfloat16* __restrict__ xb, int nf4,
    const int* __restrict__ dst, int* __restrict__ deg, int E,
    const float* __restrict__ Wl0, const float* __restrict__ bl0,
    const float* __restrict__ Wr0, const float* __restrict__ br0,
    const float* __restrict__ Ws0, const float* __restrict__ bs0,
    const float* __restrict__ Wl1, const float* __restrict__ bl1,
    const float* __restrict__ Wr1, const float* __restrict__ br1,
    const float* __restrict__ Ws1, const float* __restrict__ bs1,
    const float* __restrict__ Wl2, const float* __restrict__ bl2,
    const float* __restrict__ Wr2, const float* __restrict__ br2,
    const float* __restrict__ Ws2, const float* __restrict__ bs2,
    __hip_bfloat16* __restrict__ Wt0, float* __restrict__ bc0,
    __hip_bfloat16* __restrict__ Wt1, float* __restrict__ bc1,
    __hip_bfloat16* __restrict__ Wt2, float* __restrict__ bc2) {
    int idx = blockIdx.x * 256 + threadIdx.x;
    if (idx < nf4) {                                 // ---- f2b: x -> xb (4/thread)
        float4 v = ((const float4*)x)[idx];
        bh4 o;
        o.x = __float2bfloat16(v.x); o.y = __float2bfloat16(v.y);
        o.z = __float2bfloat16(v.z); o.w = __float2bfloat16(v.w);
        ((bh4*)xb)[idx] = o;
        return;
    }
    idx -= nf4;
    if (idx < TT) {                                  // ---- weight prep
        float v = 0.f, bb = 0.f;
        if (idx < T0) {                              // layer 0: K=128, Npad=768
            int n = idx / DIN, k = idx % DIN;
            if (n < 256)      { v = Wl0[(size_t)k * 256 + n];       bb = bl0[n]; }
            else if (n < 512) { v = Wr0[(size_t)k * 256 + n - 256]; bb = br0[n - 256]; }
            else              { v = Ws0[(size_t)k * 256 + n - 512]; bb = bs0[n - 512]; }
            Wt0[idx] = __float2bfloat16(v);
            if (k == 0) bc0[n] = bb;
        } else if (idx < T0 + T1) {                  // layer 1: K=256, Npad=768
            int i = idx - T0, n = i / HC, k = i % HC;
            if (n < 256)      { v = Wl1[(size_t)k * 256 + n];       bb = bl1[n]; }
            else if (n < 512) { v = Wr1[(size_t)k * 256 + n - 256]; bb = br1[n - 256]; }
            else              { v = Ws1[(size_t)k * 256 + n - 512]; bb = bs1[n - 512]; }
            Wt1[i] = __float2bfloat16(v);
            if (k == 0) bc1[n] = bb;
        } else {                                     // layer 2: K=256, Npad=384
            int i = idx - T0 - T1, n = i / HC, k = i % HC;
            if (n < 160)      { v = Wl2[(size_t)k * 160 + n];       bb = bl2[n]; }
            else if (n < 320) { v = Wr2[(size_t)k * 160 + n - 160]; bb = br2[n - 160]; }
            else if (n < 360) { v = Ws2[(size_t)k * 40 + n - 320];  bb = bs2[n - 320]; }
            Wt2[i] = __float2bfloat16(v);
            if (k == 0) bc2[n] = bb;
        }
        return;
    }
    idx -= TT;
    if (idx < E) atomicAdd(&deg[dst[idx]], 1);       // ---- dst histogram
}

// ---------------------------------------------------------------------------
// CSR scan: per-block exclusive scan (scan1), then merged offset+add (scan23).
// ---------------------------------------------------------------------------
__global__ __launch_bounds__(256)
void scan1_kernel(int* __restrict__ a, int* __restrict__ bsum, int n) {
    const int tid = threadIdx.x;
    const int i = blockIdx.x * 256 + tid;
    const int lane = tid & 63, w = tid >> 6;
    int v = (i < n) ? (a[i] + 1) : 0;
    int x = v;
#pragma unroll
    for (int s = 1; s < 64; s <<= 1) { int t = __shfl_up(x, s); if (lane >= s) x += t; }
    __shared__ int ws[4];
    if (lane == 63) ws[w] = x;
    __syncthreads();
    int bo = 0;
    if (w > 0) bo = ws[0];
    if (w > 1) bo += ws[1];
    if (w > 2) bo += ws[2];
    if (i <= n) a[i] = bo + x - v;
    if (tid == 255) bsum[blockIdx.x] = bo + x;
}

__global__ __launch_bounds__(256)
void scan23_kernel(int* __restrict__ a, const int* __restrict__ bsum, int n, int nb) {
    const int tid = threadIdx.x;
    const int lane = tid & 63, w = tid >> 6;
    int v = (tid < nb && tid < blockIdx.x) ? bsum[tid] : 0;
#pragma unroll
    for (int s = 1; s < 64; s <<= 1) v += __shfl_xor(v, s);
    __shared__ int ws[4];
    if (lane == 0) ws[w] = v;
    __syncthreads();
    int off = ws[0] + ws[1] + ws[2] + ws[3];
    int i = blockIdx.x * 256 + tid;
    if (i <= n) a[i] += off;
}

__global__ void scatter_kernel(const int* __restrict__ src, const int* __restrict__ dst,
                               const int* __restrict__ off, int* __restrict__ cursor,
                               int* __restrict__ srcs, int E, int N) {
    int e = blockIdx.x * 256 + threadIdx.x;
    if (e >= E + N) return;
    int s, d;
    if (e < E) { s = src[e]; d = dst[e]; }
    else       { s = e - E;  d = e - E; }
    int p = atomicAdd(&cursor[d], 1);
    srcs[off[d] + p] = s;
}

// ---------------------------------------------------------------------------
// GATv2 concat conv, 2 NODES PER WAVE (half-wave per node), 8 ch/lane (16B
// loads). Fixed per-edge costs (srcs read, shfl reduce, exp, clamp, loop)
// amortized over 2 edges per wave-iteration — inverse of R12's failure mode.
// Logit reduce = 3 shfl within 8-lane head groups. Divergent per-half loop
// bounds handled by exec mask. No-max softmax (clamp 50 = overflow guard).
// ---------------------------------------------------------------------------
__device__ __forceinline__ float edge_logit8(const float4& lo, const float4& hi,
                                             const float4& xrl, const float4& xrh,
                                             const float4& avl, const float4& avh) {
    float e, p;
    e = lo.x + xrl.x; e = e > 0.f ? e : NEG * e; p  = e * avl.x;
    e = lo.y + xrl.y; e = e > 0.f ? e : NEG * e; p += e * avl.y;
    e = lo.z + xrl.z; e = e > 0.f ? e : NEG * e; p += e * avl.z;
    e = lo.w + xrl.w; e = e > 0.f ? e : NEG * e; p += e * avl.w;
    e = hi.x + xrh.x; e = e > 0.f ? e : NEG * e; p += e * avh.x;
    e = hi.y + xrh.y; e = e > 0.f ? e : NEG * e; p += e * avh.y;
    e = hi.z + xrh.z; e = e > 0.f ? e : NEG * e; p += e * avh.z;
    e = hi.w + xrh.w; e = e > 0.f ? e : NEG * e; p += e * avh.w;
    p += __shfl_xor(p, 1);
    p += __shfl_xor(p, 2);
    p += __shfl_xor(p, 4);
    return fminf(p, 50.f);
}

template<bool BF16OUT>
__global__ __launch_bounds__(256)
void gat_conv_cat(const __hip_bfloat16* __restrict__ XL, const __hip_bfloat16* __restrict__ XR,
                  const __hip_bfloat16* __restrict__ SK, const float* __restrict__ att,
                  const float* __restrict__ bc,
                  const int* __restrict__ off, const int* __restrict__ srcs,
                  void* __restrict__ OUTv, int N, int RS) {
    const int lane = threadIdx.x & 63;
    const int half = lane >> 5, sub = lane & 31;
    const int n = blockIdx.x * 8 + (threadIdx.x >> 6) * 2 + half;
    if (n >= N) return;                            // uniform per half-wave; shfl groups intact
    const int cb = sub << 3;                       // 8 channels per lane
    float4 xrl, xrh;
    ldb8(XR + (size_t)n * RS + cb, xrl, xrh);
    const float4 avl = ld4(att + cb), avh = ld4(att + cb + 4);
    float z = 0.f;
    f32x4 al = {0.f, 0.f, 0.f, 0.f}, ah = {0.f, 0.f, 0.f, 0.f};
    int j = off[n];
    const int e1 = off[n + 1];
    for (; j + 1 < e1; j += 2) {
        int s0 = srcs[j], s1 = srcs[j + 1];
        float4 l0, h0, l1, h1;
        ldb8(XL + (size_t)s0 * RS + cb, l0, h0);
        ldb8(XL + (size_t)s1 * RS + cb, l1, h1);
        float a0 = __expf(edge_logit8(l0, h0, xrl, xrh, avl, avh));
        float a1 = __expf(edge_logit8(l1, h1, xrl, xrh, avl, avh));
        z += a0;
        al[0] += a0 * l0.x; al[1] += a0 * l0.y; al[2] += a0 * l0.z; al[3] += a0 * l0.w;
        ah[0] += a0 * h0.x; ah[1] += a0 * h0.y; ah[2] += a0 * h0.z; ah[3] += a0 * h0.w;
        z += a1;
        al[0] += a1 * l1.x; al[1] += a1 * l1.y; al[2] += a1 * l1.z; al[3] += a1 * l1.w;
        ah[0] += a1 * h1.x; ah[1] += a1 * h1.y; ah[2] += a1 * h1.z; ah[3] += a1 * h1.w;
    }
    if (j < e1) {
        int s0 = srcs[j];
        float4 l0, h0;
        ldb8(XL + (size_t)s0 * RS + cb, l0, h0);
        float a0 = __expf(edge_logit8(l0, h0, xrl, xrh, avl, avh));
        z += a0;
        al[0] += a0 * l0.x; al[1] += a0 * l0.y; al[2] += a0 * l0.z; al[3] += a0 * l0.w;
        ah[0] += a0 * h0.x; ah[1] += a0 * h0.y; ah[2] += a0 * h0.z; ah[3] += a0 * h0.w;
    }
    float inv = 1.f / z;
    float4 skl, skh;
    ldb8(SK + (size_t)n * RS + cb, skl, skh);
    const float4 bbl = ld4(bc + cb), bbh = ld4(bc + cb + 4);
    float r0 = al[0] * inv + bbl.x + skl.x;
    float r1 = al[1] * inv + bbl.y + skl.y;
    float r2 = al[2] * inv + bbl.z + skl.z;
    float r3 = al[3] * inv + bbl.w + skl.w;
    float r4 = ah[0] * inv + bbh.x + skh.x;
    float r5 = ah[1] * inv + bbh.y + skh.y;
    float r6 = ah[2] * inv + bbh.z + skh.z;
    float r7 = ah[3] * inv + bbh.w + skh.w;
    if (BF16OUT) {
        bh8v o;
        o.a.x = __float2bfloat16(r0); o.a.y = __float2bfloat16(r1);
        o.a.z = __float2bfloat16(r2); o.a.w = __float2bfloat16(r3);
        o.b.x = __float2bfloat16(r4); o.b.y = __float2bfloat16(r5);
        o.b.z = __float2bfloat16(r6); o.b.w = __float2bfloat16(r7);
        *(bh8v*)((__hip_bfloat16*)OUTv + (size_t)n * HC + cb) = o;
    } else {
        float* o = (float*)OUTv + (size_t)n * HC + cb;
        *(float4*)o       = make_float4(r0, r1, r2, r3);
        *(float4*)(o + 4) = make_float4(r4, r5, r6, r7);
    }
}

// ---------------------------------------------------------------------------
// GATv2 aggregation, mean layer (H=4, OUT=40). 2 nodes/wave, all 64 lanes.
// ---------------------------------------------------------------------------
__device__ __forceinline__ void mean_edge(const __hip_bfloat16* __restrict__ XL, size_t srow,
                                          int bm_ch, int bt_ch,
                                          const float4& xr4, float xrt,
                                          const float4& av4, float avt,
                                          float& z, float& c0, float& c1, float& c2,
                                          float& c3, float& c4) {
    float4 x4 = ldb4(XL + srow + bm_ch);
    float xt = __bfloat162float(XL[srow + bt_ch]);
    float e0 = x4.x + xr4.x; e0 = e0 > 0.f ? e0 : NEG * e0;
    float e1 = x4.y + xr4.y; e1 = e1 > 0.f ? e1 : NEG * e1;
    float e2 = x4.z + xr4.z; e2 = e2 > 0.f ? e2 : NEG * e2;
    float e3 = x4.w + xr4.w; e3 = e3 > 0.f ? e3 : NEG * e3;
    float et = xt + xrt;     et = et > 0.f ? et : NEG * et;
    float p = e0 * av4.x + e1 * av4.y + e2 * av4.z + e3 * av4.w + et * avt;
    p += __shfl_xor(p, 1);
    p += __shfl_xor(p, 2);
    p += __shfl_xor(p, 4);
    p = fminf(p, 50.f);
    float a = __expf(p);
    z += a;
    c0 += a * x4.x; c1 += a * x4.y; c2 += a * x4.z; c3 += a * x4.w; c4 += a * xt;
}

__global__ __launch_bounds__(256)
void gat_conv_mean(const __hip_bfloat16* __restrict__ XL, const __hip_bfloat16* __restrict__ XR,
                   const __hip_bfloat16* __restrict__ SK, const float* __restrict__ att,
                   const float* __restrict__ bc,
                   const int* __restrict__ off, const int* __restrict__ srcs,
                   float* __restrict__ OUT, int N, int RS) {
    const int lane = threadIdx.x & 63;
    const int half = lane >> 5, sub = lane & 31;
    const int n = blockIdx.x * 8 + (threadIdx.x >> 6) * 2 + half;
    if (n >= N) return;
    const int hd = sub >> 3, q = sub & 7;
    const int bm_ch = hd * OUTC + q * 4;
    const int bt_ch = hd * OUTC + 32 + q;
    const size_t nrow = (size_t)n * RS;
    const float4 xr4 = ldb4(XR + nrow + bm_ch);
    const float xrt = __bfloat162float(XR[nrow + bt_ch]);
    const float4 av4 = ld4(att + bm_ch);
    const float avt = att[bt_ch];
    float z = 0.f, c0 = 0.f, c1 = 0.f, c2 = 0.f, c3 = 0.f, c4 = 0.f;
    int j = off[n];
    const int e1 = off[n + 1];
    for (; j + 3 < e1; j += 4) {
        size_t r0 = (size_t)srcs[j] * RS,     r1 = (size_t)srcs[j + 1] * RS;
        size_t r2 = (size_t)srcs[j + 2] * RS, r3 = (size_t)srcs[j + 3] * RS;
        mean_edge(XL, r0, bm_ch, bt_ch, xr4, xrt, av4, avt, z, c0, c1, c2, c3, c4);
        mean_edge(XL, r1, bm_ch, bt_ch, xr4, xrt, av4, avt, z, c0, c1, c2, c3, c4);
        mean_edge(XL, r2, bm_ch, bt_ch, xr4, xrt, av4, avt, z, c0, c1, c2, c3, c4);
        mean_edge(XL, r3, bm_ch, bt_ch, xr4, xrt, av4, avt, z, c0, c1, c2, c3, c4);
    }
    for (; j < e1; ++j)
        mean_edge(XL, (size_t)srcs[j] * RS, bm_ch, bt_ch, xr4, xrt, av4, avt, z, c0, c1, c2, c3, c4);

    float inv = 1.f / z;
    float r0 = c0 * inv, r1 = c1 * inv, r2 = c2 * inv, r3 = c3 * inv, r4 = c4 * inv;
    r0 += __shfl_xor(r0, 8); r0 += __shfl_xor(r0, 16);
    r1 += __shfl_xor(r1, 8); r1 += __shfl_xor(r1, 16);
    r2 += __shfl_xor(r2, 8); r2 += __shfl_xor(r2, 16);
    r3 += __shfl_xor(r3, 8); r3 += __shfl_xor(r3, 16);
    r4 += __shfl_xor(r4, 8); r4 += __shfl_xor(r4, 16);
    if (hd == 0) {
        int o = q << 2;
        float4 sk4 = ldb4(SK + nrow + o);
        float skt = __bfloat162float(SK[nrow + 32 + q]);
        float4 rv;
        rv.x = r0 * 0.25f + bc[o + 0] + sk4.x;
        rv.y = r1 * 0.25f + bc[o + 1] + sk4.y;
        rv.z = r2 * 0.25f + bc[o + 2] + sk4.z;
        rv.w = r3 * 0.25f + bc[o + 3] + sk4.w;
        *(float4*)(OUT + (size_t)n * OUTC + o) = rv;
        OUT[(size_t)n * OUTC + 32 + q] = r4 * 0.25f + bc[32 + q] + skt;
    }
}

// ---------------------------------------------------------------------------
// BatchNorm stats (separate pass — fusing into conv regressed twice: R6, R8).
// ---------------------------------------------------------------------------
__global__ __launch_bounds__(256)
void bn_stats_f(const float* __restrict__ X, float* __restrict__ sums,
                float* __restrict__ sqs, int N) {
    int c = threadIdx.x;
    float s = 0.f, qq = 0.f;
    for (int n = blockIdx.x; n < N; n += gridDim.x) {
        float v = X[(size_t)n * HC + c];
        s += v; qq += v * v;
    }
    atomicAdd(&sums[c], s);
    atomicAdd(&sqs[c], qq);
}

__global__ __launch_bounds__(256)
void bn_stats_b(const __hip_bfloat16* __restrict__ X, float* __restrict__ sums,
                float* __restrict__ sqs, int N) {
    int c = threadIdx.x;
    float s = 0.f, qq = 0.f;
    for (int n = blockIdx.x; n < N; n += gridDim.x) {
        float v = __bfloat162float(X[(size_t)n * HC + c]);
        s += v; qq += v * v;
    }
    atomicAdd(&sums[c], s);
    atomicAdd(&sqs[c], qq);
}

// ---------------------------------------------------------------------------
// BN finalize (per-block, in LDS) + apply + ReLU -> bf16 (verified R8).
// ---------------------------------------------------------------------------
template<bool BF16IN>
__global__ __launch_bounds__(256)
void bn_apply_relu(const void* __restrict__ Xv, const float* __restrict__ sums,
                   const float* __restrict__ sqs, const float* __restrict__ g,
                   const float* __restrict__ be, __hip_bfloat16* __restrict__ Y,
                   int N, int n4) {
    __shared__ float scs[256], shs[256];
    {
        int c = threadIdx.x;
        float mean = sums[c] / (float)N;
        float var = sqs[c] / (float)N - mean * mean;
        float iv = rsqrtf(var + BNEPS);
        float sc = g[c] * iv;
        scs[c] = sc;
        shs[c] = be[c] - mean * sc;
    }
    __syncthreads();
    for (int i = blockIdx.x * blockDim.x + threadIdx.x; i < n4; i += gridDim.x * blockDim.x) {
        int c4 = (i & 63) << 2;
        float4 v;
        if (BF16IN) v = ldb4((const __hip_bfloat16*)Xv + (size_t)i * 4);
        else        v = ((const float4*)Xv)[i];
        float4 s = ld4(scs + c4);
        float4 h = ld4(shs + c4);
        bh4 r;
        r.x = __float2bfloat16(fmaxf(v.x * s.x + h.x, 0.f));
        r.y = __float2bfloat16(fmaxf(v.y * s.y + h.y, 0.f));
        r.z = __float2bfloat16(fmaxf(v.z * s.z + h.z, 0.f));
        r.w = __float2bfloat16(fmaxf(v.w * s.w + h.w, 0.f));
        ((bh4*)Y)[i] = r;
    }
}

// ---------------------------------------------------------------------------
extern "C" void kernel_launch(void* const* d_in, const int* in_sizes, int n_in,
                              void* d_out, int out_size, void* d_ws, size_t ws_size,
                              hipStream_t stream) {
    const int N = in_sizes[0] / DIN;    // 50000
    const int E = in_sizes[1];          // 400000
    const int Et = E + N;

    const float* x   = (const float*)d_in[0];
    const int* src   = (const int*)d_in[1];
    const int* dst   = (const int*)d_in[2];
    const float* Wl0 = (const float*)d_in[3];  const float* bl0 = (const float*)d_in[4];
    const float* Wr0 = (const float*)d_in[5];  const float* br0 = (const float*)d_in[6];
    const float* att0= (const float*)d_in[7];  const float* bc0 = (const float*)d_in[8];
    const float* Ws0 = (const float*)d_in[9];  const float* bs0 = (const float*)d_in[10];
    const float* g0  = (const float*)d_in[11]; const float* be0 = (const float*)d_in[12];
    const float* Wl1 = (const float*)d_in[13]; const float* bl1 = (const float*)d_in[14];
    const float* Wr1 = (const float*)d_in[15]; const float* br1 = (const float*)d_in[16];
    const float* att1= (const float*)d_in[17]; const float* bc1 = (const float*)d_in[18];
    const float* Ws1 = (const float*)d_in[19]; const float* bs1 = (const float*)d_in[20];
    const float* g1  = (const float*)d_in[21]; const float* be1 = (const float*)d_in[22];
    const float* Wl2 = (const float*)d_in[23]; const float* bl2 = (const float*)d_in[24];
    const float* Wr2 = (const float*)d_in[25]; const float* br2 = (const float*)d_in[26];
    const float* att2= (const float*)d_in[27]; const float* bc2 = (const float*)d_in[28];
    const float* Ws2 = (const float*)d_in[29]; const float* bs2 = (const float*)d_in[30];

    float* outh = (float*)d_out;                    // h [N,256] (layer-1 conv out, f32)
    float* outy = outh + (size_t)N * HC;            // out [N,40]

    // workspace carve (~132 MB)
    __hip_bfloat16* Y  = (__hip_bfloat16*)d_ws;     // [N][768] bf16 GEMM out
    __hip_bfloat16* xb = Y + (size_t)N * 768;       // [N][256] bf16 activations
    __hip_bfloat16* P  = xb + (size_t)N * HC;       // [N][256] bf16 x1pre staging
    __hip_bfloat16* Wt0 = P + (size_t)N * HC;       // [768*128]
    __hip_bfloat16* Wt1 = Wt0 + T0;                 // [768*256]
    __hip_bfloat16* Wt2 = Wt1 + T1;                 // [384*256]
    float* bcc0 = (float*)(Wt2 + T2);               // [768]
    float* bcc1 = bcc0 + 768;                       // [768]
    float* bcc2 = bcc1 + 768;                       // [384]
    int* off    = (int*)(bcc2 + 384);               // [N+1]
    int* cursor = off + (N + 1);                    // [N]
    float* bn   = (float*)(cursor + N);             // [1024]: s0,q0 | s1,q1
    int* srcs   = (int*)(bn + 1024);                // [Et]
    int* bsum   = srcs + Et;                        // [256]

    // ---- single memset: off + cursor + both BN accumulators ----
    hipMemsetAsync(off, 0, ((size_t)(2 * N + 1) + 1024) * sizeof(int), stream);

    // ---- fused setup (f2b | weight prep | histogram) ----
    const int nf4 = N * DIN / 4;
    const int setup_items = nf4 + TT + E;
    setup_kernel<<<(setup_items + 255) / 256, 256, 0, stream>>>(
        x, xb, nf4, dst, off, E,
        Wl0, bl0, Wr0, br0, Ws0, bs0, Wl1, bl1, Wr1, br1, Ws1, bs1,
        Wl2, bl2, Wr2, br2, Ws2, bs2, Wt0, bcc0, Wt1, bcc1, Wt2, bcc2);

    // ---- CSR scan + scatter ----
    const int nb_scan = (N + 1 + 255) / 256;        // 196
    scan1_kernel<<<nb_scan, 256, 0, stream>>>(off, bsum, N);
    scan23_kernel<<<nb_scan, 256, 0, stream>>>(off, bsum, N, nb_scan);
    scatter_kernel<<<(Et + 255) / 256, 256, 0, stream>>>(src, dst, off, cursor, srcs, E, N);

    const int gmy = (N + 127) / 128;                // 391 row tiles
    const int convGrid = (N + 7) / 8;               // 2 nodes/wave, 8 nodes/block
    const int meanGrid = (N + 7) / 8;
    const int nwgA = 6 * gmy, qA = nwgA / 8, rA = nwgA % 8;
    const int nwgC = 3 * gmy, qC = nwgC / 8, rC = nwgC % 8;

    // ---- layer 0 (K=128, Npad=768) ----
    gemm_mfma<<<nwgA, 256, 0, stream>>>(xb, Wt0, bcc0, Y, N, DIN, 768, 6, qA, rA);
    gat_conv_cat<true><<<convGrid, 256, 0, stream>>>(Y, Y + 256, Y + 512, att0, bc0,
                                                     off, srcs, P, N, 768);
    bn_stats_b<<<1024, 256, 0, stream>>>(P, bn, bn + 256, N);
    bn_apply_relu<true><<<2048, 256, 0, stream>>>(P, bn, bn + 256, g0, be0, xb, N, N * (HC / 4));

    // ---- layer 1 (K=256, Npad=768) ----
    gemm_mfma<<<nwgA, 256, 0, stream>>>(xb, Wt1, bcc1, Y, N, HC, 768, 6, qA, rA);
    gat_conv_cat<false><<<convGrid, 256, 0, stream>>>(Y, Y + 256, Y + 512, att1, bc1,
                                                      off, srcs, outh, N, 768);
    bn_stats_f<<<1024, 256, 0, stream>>>(outh, bn + 512, bn + 768, N);
    bn_apply_relu<false><<<2048, 256, 0, stream>>>(outh, bn + 512, bn + 768, g1, be1, xb, N, N * (HC / 4));

    // ---- layer 2 (K=256, Npad=384, cols: XL2[0:160) XR2[160:320) SK2[320:360)) ----
    gemm_mfma<<<nwgC, 256, 0, stream>>>(xb, Wt2, bcc2, Y, N, HC, 384, 3, qC, rC);
    gat_conv_mean<<<meanGrid, 256, 0, stream>>>(Y, Y + 160, Y + 320, att2, bc2, off, srcs,
                                                outy, N, 384);
}